// Round 4
// baseline (337.127 us; speedup 1.0000x reference)
//
#include <hip/hip_runtime.h>
#include <hip/hip_bf16.h>

// Problem constants: B=64, C=256, H=W=28, N=784
#define BB   64
#define CC   256
#define NPIX 784
#define BNP  (BB * NPIX)   // 50176
#define SLOTS 128

// ---------------------------------------------------------------------------
// K1: transpose z1,z2 [B,C,N] -> zt[2,B,N,C] + fused squared norms (no
// atomics: each block owns ALL 256 channels of a 64-pixel tile).
// grid: bx = (arr*64 + b)*13 + nt ; 2*64*13 = 1664 blocks.
// LDS [n][257]: stage-writes and reads both analyzed 2-way max (free).
// ---------------------------------------------------------------------------
__global__ __launch_bounds__(256) void zt_k(
    const float* __restrict__ z1, const float* __restrict__ z2,
    float* __restrict__ zt, float* __restrict__ zn2) {
    __shared__ float lds[64 * 257];
    __shared__ float part[4][64];

    int bx = blockIdx.x;
    int nt = bx % 13;
    int t  = bx / 13;
    int b  = t & 63;
    int arr = t >> 6;                       // 0 = z1, 1 = z2
    int nlim = (nt == 12) ? 16 : 64;        // 13*64 = 832 > 784

    const float* in = (arr ? z2 : z1) + (size_t)b * CC * NPIX + nt * 64;
    int tid  = threadIdx.x;
    int n4   = tid & 15;                    // float4 index along n
    int subc = tid >> 4;                    // channel sub-index
    int nn   = 4 * n4;

    // stage: coalesced float4 along n; scatter scalars to [n][c]
#pragma unroll
    for (int k = 0; k < 16; k++) {
        int c = subc + 16 * k;
        float4 v = {0.f, 0.f, 0.f, 0.f};
        if (nn < nlim) v = *(const float4*)(in + (size_t)c * NPIX + nn);
        lds[(nn + 0) * 257 + c] = v.x;
        lds[(nn + 1) * 257 + c] = v.y;
        lds[(nn + 2) * 257 + c] = v.z;
        lds[(nn + 3) * 257 + c] = v.w;
    }
    __syncthreads();

    // squared-norm partials: thread (nl, cq) sums 64 channels
    {
        int nl = tid & 63, cq = tid >> 6;
        float s = 0.f;
#pragma unroll 8
        for (int sc = 0; sc < 64; sc++) {
            float v = lds[nl * 257 + cq * 64 + sc];
            s = fmaf(v, v, s);
        }
        part[cq][nl] = s;
    }

    // transposed write: 16 consecutive lanes write 256 B contiguous
    float* outb = zt + ((size_t)arr * BB + b) * ((size_t)NPIX * CC)
                     + (size_t)nt * 64 * CC;
    int lane = tid & 63, wv = tid >> 6;
    int c4 = lane & 15, nq = lane >> 4;
#pragma unroll
    for (int cq2 = 0; cq2 < 4; cq2++) {
#pragma unroll
        for (int nb = 0; nb < 4; nb++) {
            int n = 16 * wv + 4 * nb + nq;
            if (n < nlim) {
                int cc0 = 4 * (16 * cq2 + c4);
                float4 v;
                v.x = lds[n * 257 + cc0 + 0];
                v.y = lds[n * 257 + cc0 + 1];
                v.z = lds[n * 257 + cc0 + 2];
                v.w = lds[n * 257 + cc0 + 3];
                *(float4*)(outb + (size_t)n * CC + cc0) = v;
            }
        }
    }
    __syncthreads();
    if (tid < nlim) {
        zn2[(size_t)arr * BNP + (size_t)b * NPIX + nt * 64 + tid] =
            part[0][tid] + part[1][tid] + part[2][tid] + part[3][tid];
    }
}

// ---------------------------------------------------------------------------
// K2: masked pair cosine sims. Block = (loss, b, 4 consecutive i); wave per i.
// y rows staged in-block from ORIGINAL layout (L2/L3-reused float4 loads);
// na computed in-register. Slot-direct rounds: 4 rounds x 4 groups cover the
// 16-slot candidate box, all loads of a round issue together (no ctz chain).
// Mask math is byte-identical to the R2 kernel (absmax == 0).
// ---------------------------------------------------------------------------
__global__ __launch_bounds__(256) void pairs_k(
    const float* __restrict__ y1, const float* __restrict__ y2,
    const float* __restrict__ zt, const float* __restrict__ zn2,
    const float* __restrict__ g1g, const float* __restrict__ g2g,
    double* __restrict__ acc) {
    __shared__ float  ylds[4 * 256];
    __shared__ double shs[4];
    __shared__ int    shc[4];

    int tid  = threadIdx.x;
    int lane = tid & 63, wv = tid >> 6;
    int bx   = blockIdx.x;                   // [0, 25088)
    int loss = (bx >= 12544) ? 1 : 0;
    int rem  = bx - loss * 12544;
    int b    = rem / 196;
    int ig   = rem - b * 196;
    int i0   = 4 * ig;

    // stage y[b, :, i0..i0+3]: one float4 per thread (c = tid)
    const float* Yg = (loss ? y2 : y1) + (size_t)b * CC * NPIX;
    {
        float4 v = *(const float4*)(Yg + (size_t)tid * NPIX + i0);
        ylds[        tid] = v.x;
        ylds[256  + tid] = v.y;
        ylds[512  + tid] = v.z;
        ylds[768  + tid] = v.w;
    }

    const float* g1 = g1g + (size_t)b * 2 * NPIX;
    const float* g2 = g2g + (size_t)b * 2 * NPIX;
    int i = i0 + wv;
    float g1y = g1[i];
    float g1x = g1[NPIX + i];

    // bin = norm(grid[...,1,1] - grid[...,0,0])  (bit-exact chain)
    const float* gb = loss ? g2 : g1;
    float d0  = gb[29] - gb[0];
    float d1  = gb[NPIX + 29] - gb[NPIX];
    float bin = __fsqrt_rn(__fadd_rn(__fmul_rn(d0, d0), __fmul_rn(d1, d1)));

    // candidate box in grid2 index space (guard-widened superset; exact below)
    float t2y = g2[0], t2x = g2[NPIX];
    float s2y = g2[28] - g2[0];
    float s2x = g2[NPIX + 1] - g2[NPIX];
    float r  = 0.7f * bin * 1.0002f + 1e-4f;
    float cy = (g1y - t2y) / s2y;
    float cx = (g1x - t2x) / s2x;
    float ry = r / s2y + 0.05f;
    float rx = r / s2x + 0.05f;
    int jy0 = max(0,  (int)ceilf(cy - ry));
    int jy1 = min(27, (int)floorf(cy + ry));
    int jx0 = max(0,  (int)ceilf(cx - rx));
    int jx1 = min(27, (int)floorf(cx + rx));
    int dyr = jy1 - jy0, dxr = jx1 - jx0;

    int dyl = lane >> 2, dxl = lane & 3;
    bool pass = false;
    if (lane < 16 && dyl <= dyr && dxl <= dxr) {
        int jc = (jy0 + dyl) * 28 + jx0 + dxl;
        float dy = g1y - g2[jc];
        float dx = g1x - g2[NPIX + jc];
        float d  = __fsqrt_rn(__fadd_rn(__fmul_rn(dy, dy), __fmul_rn(dx, dx)));
        pass = (__fdiv_rn(d, bin) <= 0.7f);   // bit-exact mask decision
    }
    unsigned long long m = __ballot(pass);
    int cnt = __builtin_popcountll(m);

    __syncthreads();

    int gl = lane & 15, g = lane >> 4;
    const float4* Yr = (const float4*)(ylds + wv * 256);
    float4 ya = Yr[gl], yb = Yr[gl + 16], yc = Yr[gl + 32], yd = Yr[gl + 48];

    // na from registers (16-lane group reduce)
    float p = ya.x * ya.x;
    p = fmaf(ya.y, ya.y, p); p = fmaf(ya.z, ya.z, p); p = fmaf(ya.w, ya.w, p);
    p = fmaf(yb.x, yb.x, p); p = fmaf(yb.y, yb.y, p); p = fmaf(yb.z, yb.z, p);
    p = fmaf(yb.w, yb.w, p);
    p = fmaf(yc.x, yc.x, p); p = fmaf(yc.y, yc.y, p); p = fmaf(yc.z, yc.z, p);
    p = fmaf(yc.w, yc.w, p);
    p = fmaf(yd.x, yd.x, p); p = fmaf(yd.y, yd.y, p); p = fmaf(yd.z, yd.z, p);
    p = fmaf(yd.w, yd.w, p);
#pragma unroll
    for (int off = 1; off < 16; off <<= 1) p += __shfl_xor(p, off);
    float na = __fsqrt_rn(p);

    const float* Zb = zt  + ((size_t)(1 - loss) * BB + b) * ((size_t)NPIX * CC);
    const float* zn = zn2 + ((size_t)(1 - loss) * BB + b) * NPIX;

    double ssum = 0.0;
#pragma unroll
    for (int rr = 0; rr < 4; rr++) {
        int mr = (int)((m >> (4 * rr)) & 15ull);
        if (!mr) continue;
        int s   = 4 * rr + g;                 // this group's slot
        bool val = (mr >> g) & 1;
        int j = val ? ((jy0 + (s >> 2)) * 28 + jx0 + (s & 3)) : 0;
        const float4* Z4 = (const float4*)(Zb + (size_t)j * CC);
        float4 za = Z4[gl], zb_ = Z4[gl + 16], zc = Z4[gl + 32], zd = Z4[gl + 48];
        float nb2 = zn[j];
        float dp = ya.x * za.x;
        dp = fmaf(ya.y, za.y, dp); dp = fmaf(ya.z, za.z, dp);
        dp = fmaf(ya.w, za.w, dp);
        dp = fmaf(yb.x, zb_.x, dp); dp = fmaf(yb.y, zb_.y, dp);
        dp = fmaf(yb.z, zb_.z, dp); dp = fmaf(yb.w, zb_.w, dp);
        dp = fmaf(yc.x, zc.x, dp); dp = fmaf(yc.y, zc.y, dp);
        dp = fmaf(yc.z, zc.z, dp); dp = fmaf(yc.w, zc.w, dp);
        dp = fmaf(yd.x, zd.x, dp); dp = fmaf(yd.y, zd.y, dp);
        dp = fmaf(yd.z, zd.z, dp); dp = fmaf(yd.w, zd.w, dp);
#pragma unroll
        for (int off = 1; off < 16; off <<= 1) dp += __shfl_xor(dp, off);
        float den = fmaxf(na * __fsqrt_rn(nb2), 1e-8f);
        float sim = __fdividef(dp, den);
        if (val) ssum += (double)sim;
    }
    // combine the 4 groups (lanes within a group hold identical ssum)
    ssum += __shfl_xor(ssum, 16);
    ssum += __shfl_xor(ssum, 32);

    if (lane == 0) { shs[wv] = ssum; shc[wv] = cnt; }
    __syncthreads();
    if (tid == 0) {
        double s = shs[0] + shs[1] + shs[2] + shs[3];
        double c = (double)(shc[0] + shc[1] + shc[2] + shc[3]);
        double* slot = acc + (size_t)(bx & (SLOTS - 1)) * 4;
        atomicAdd(&slot[loss * 2],     s);
        atomicAdd(&slot[loss * 2 + 1], c);
    }
}

// ---------------------------------------------------------------------------
// K3: finalize  loss = -(S0/M0 + S1/M1)  (reduce the 128 slots)
// ---------------------------------------------------------------------------
__global__ void fin_k(const double* __restrict__ acc, float* __restrict__ out) {
    int lane = threadIdx.x;   // 64 threads
    double s0 = 0, m0 = 0, s1 = 0, m1 = 0;
    for (int s = lane; s < SLOTS; s += 64) {
        const double* p = acc + (size_t)s * 4;
        s0 += p[0]; m0 += p[1]; s1 += p[2]; m1 += p[3];
    }
#pragma unroll
    for (int off = 32; off; off >>= 1) {
        s0 += __shfl_xor(s0, off); m0 += __shfl_xor(m0, off);
        s1 += __shfl_xor(s1, off); m1 += __shfl_xor(m1, off);
    }
    if (lane == 0) out[0] = (float)(-(s0 / m0 + s1 / m1));
}

extern "C" void kernel_launch(void* const* d_in, const int* in_sizes, int n_in,
                              void* d_out, int out_size, void* d_ws, size_t ws_size,
                              hipStream_t stream) {
    const float* y1 = (const float*)d_in[0];
    const float* y2 = (const float*)d_in[1];
    const float* z1 = (const float*)d_in[2];
    const float* z2 = (const float*)d_in[3];
    const float* g1 = (const float*)d_in[4];
    const float* g2 = (const float*)d_in[5];
    float* out = (float*)d_out;

    char* ws = (char*)d_ws;
    double* acc = (double*)ws;                         // SLOTS*4 doubles = 4 KB
    float*  zn2 = (float*)(ws + 4096);                 // 2*BNP floats = 401,408 B
    float*  zt  = (float*)(ws + 4096 + 2 * BNP * sizeof(float));  // 16B aligned
    // zt: [2][B][N][C] = 2 * 12,845,056 floats = 102.8 MB

    hipMemsetAsync(acc, 0, SLOTS * 4 * sizeof(double), stream);

    // z transpose + norms: 2 arrays * 64 b * 13 n-tiles = 1664 blocks
    zt_k<<<1664, 256, 0, stream>>>(z1, z2, zt, zn2);

    // pairs: 2 losses * 64 b * 196 i-groups = 25088 blocks
    pairs_k<<<25088, 256, 0, stream>>>(y1, y2, zt, zn2, g1, g2, acc);

    fin_k<<<1, 64, 0, stream>>>(acc, out);
}

// Round 5
// 277.931 us; speedup vs baseline: 1.2130x; 1.2130x over previous
//
#include <hip/hip_runtime.h>
#include <hip/hip_bf16.h>

// Problem constants: B=64, C=256, H=W=28, N=784
#define BB   64
#define CC   256
#define NPIX 784
#define BNP  (BB * NPIX)   // 50176
#define SLOTS 128

// ---------------------------------------------------------------------------
// K1: transpose z1,z2 [B,C,N] -> zt[2,B,N,C] + fused squared norms.
// 32-pixel tiles (33 KB LDS -> 4 blocks/CU). All LDS patterns <=2-way.
// grid: bx = (arr*64 + b)*25 + nt ; 2*64*25 = 3200 blocks.
// ---------------------------------------------------------------------------
__global__ __launch_bounds__(256) void zt_k(
    const float* __restrict__ z1, const float* __restrict__ z2,
    float* __restrict__ zt, float* __restrict__ zn2) {
    __shared__ float lds[32 * 257];
    __shared__ float part[8][32];

    int bx = blockIdx.x;
    int nt = bx % 25;
    int t  = bx / 25;
    int b  = t & 63;
    int arr = t >> 6;                       // 0 = z1, 1 = z2
    int nlim = (nt == 24) ? 16 : 32;        // 24*32 + 16 = 784

    const float* in = (arr ? z2 : z1) + (size_t)b * CC * NPIX + nt * 32;
    int tid  = threadIdx.x;
    int n4   = tid & 7;                     // float4 index along n
    int subc = tid >> 3;                    // 0..31
    int nn   = 4 * n4;

    // stage: coalesced float4 along n; scatter scalars to [n][c]
#pragma unroll
    for (int k = 0; k < 8; k++) {
        int c = subc + 32 * k;
        float4 v = {0.f, 0.f, 0.f, 0.f};
        if (nn < nlim) v = *(const float4*)(in + (size_t)c * NPIX + nn);
        lds[(nn + 0) * 257 + c] = v.x;
        lds[(nn + 1) * 257 + c] = v.y;
        lds[(nn + 2) * 257 + c] = v.z;
        lds[(nn + 3) * 257 + c] = v.w;
    }
    __syncthreads();

    // squared-norm partials: thread (nl, cq) sums 32 channels
    {
        int nl = tid & 31, cq = tid >> 5;
        float s = 0.f;
#pragma unroll 8
        for (int sc = 0; sc < 32; sc++) {
            float v = lds[nl * 257 + cq * 32 + sc];
            s = fmaf(v, v, s);
        }
        part[cq][nl] = s;
    }

    // transposed write: 16 consecutive lanes write 256 B contiguous
    float* outb = zt + ((size_t)arr * BB + b) * ((size_t)NPIX * CC)
                     + (size_t)nt * 32 * CC;
    int lane = tid & 63, wv = tid >> 6;
    int c4 = lane & 15, nq = (lane >> 4) & 3;
#pragma unroll
    for (int cq2 = 0; cq2 < 4; cq2++) {
#pragma unroll
        for (int nb = 0; nb < 2; nb++) {
            int n = 8 * wv + 4 * nb + nq;
            if (n < nlim) {
                int cc0 = 64 * cq2 + 4 * c4;
                float4 v;
                v.x = lds[n * 257 + cc0 + 0];
                v.y = lds[n * 257 + cc0 + 1];
                v.z = lds[n * 257 + cc0 + 2];
                v.w = lds[n * 257 + cc0 + 3];
                *(float4*)(outb + (size_t)n * CC + cc0) = v;
            }
        }
    }
    __syncthreads();
    if (tid < nlim) {
        float s = part[0][tid] + part[1][tid] + part[2][tid] + part[3][tid]
                + part[4][tid] + part[5][tid] + part[6][tid] + part[7][tid];
        zn2[(size_t)arr * BNP + (size_t)b * NPIX + nt * 32 + tid] = s;
    }
}

// ---------------------------------------------------------------------------
// K2: masked pair cosine sims. Block = (loss, b, 16 consecutive i),
// 1024 threads = 16 waves, wave per i. y staged via FULL-64B-line reads
// (exact 103 MB y fetch, zero waste). Per-wave compute identical to R3's
// verified slot-direct rounds; mask math byte-identical (absmax == 0).
// ---------------------------------------------------------------------------
__global__ __launch_bounds__(1024, 8) void pairs_k(
    const float* __restrict__ y1, const float* __restrict__ y2,
    const float* __restrict__ zt, const float* __restrict__ zn2,
    const float* __restrict__ g1g, const float* __restrict__ g2g,
    double* __restrict__ acc) {
    __shared__ float  ylds[16 * 256];     // [i][c]
    __shared__ double shs[16];
    __shared__ int    shc[16];

    int tid  = threadIdx.x;
    int lane = tid & 63, wv = tid >> 6;
    int bx   = blockIdx.x;                   // [0, 6272)
    int loss = (bx >= 3136) ? 1 : 0;
    int rem  = bx - loss * 3136;
    int b    = rem / 49;
    int ig   = rem - b * 49;
    int i0   = 16 * ig;

    // stage y[b, :, i0..i0+15]: thread c<256 reads the full 64B line
    const float* Yg = (loss ? y2 : y1) + (size_t)b * CC * NPIX;
    if (tid < 256) {
        const float* row = Yg + (size_t)tid * NPIX + i0;
#pragma unroll
        for (int q = 0; q < 4; q++) {
            float4 v = *(const float4*)(row + 4 * q);
            ylds[(4 * q + 0) * 256 + tid] = v.x;
            ylds[(4 * q + 1) * 256 + tid] = v.y;
            ylds[(4 * q + 2) * 256 + tid] = v.z;
            ylds[(4 * q + 3) * 256 + tid] = v.w;
        }
    }

    const float* g1 = g1g + (size_t)b * 2 * NPIX;
    const float* g2 = g2g + (size_t)b * 2 * NPIX;
    int i = i0 + wv;
    float g1y = g1[i];
    float g1x = g1[NPIX + i];

    // bin = norm(grid[...,1,1] - grid[...,0,0])  (bit-exact chain)
    const float* gb = loss ? g2 : g1;
    float d0  = gb[29] - gb[0];
    float d1  = gb[NPIX + 29] - gb[NPIX];
    float bin = __fsqrt_rn(__fadd_rn(__fmul_rn(d0, d0), __fmul_rn(d1, d1)));

    // candidate box in grid2 index space (guard-widened superset; exact below)
    float t2y = g2[0], t2x = g2[NPIX];
    float s2y = g2[28] - g2[0];
    float s2x = g2[NPIX + 1] - g2[NPIX];
    float r  = 0.7f * bin * 1.0002f + 1e-4f;
    float cy = (g1y - t2y) / s2y;
    float cx = (g1x - t2x) / s2x;
    float ry = r / s2y + 0.05f;
    float rx = r / s2x + 0.05f;
    int jy0 = max(0,  (int)ceilf(cy - ry));
    int jy1 = min(27, (int)floorf(cy + ry));
    int jx0 = max(0,  (int)ceilf(cx - rx));
    int jx1 = min(27, (int)floorf(cx + rx));
    int dyr = jy1 - jy0, dxr = jx1 - jx0;

    int dyl = lane >> 2, dxl = lane & 3;
    bool pass = false;
    if (lane < 16 && dyl <= dyr && dxl <= dxr) {
        int jc = (jy0 + dyl) * 28 + jx0 + dxl;
        float dy = g1y - g2[jc];
        float dx = g1x - g2[NPIX + jc];
        float d  = __fsqrt_rn(__fadd_rn(__fmul_rn(dy, dy), __fmul_rn(dx, dx)));
        pass = (__fdiv_rn(d, bin) <= 0.7f);   // bit-exact mask decision
    }
    unsigned long long m = __ballot(pass);
    int cnt = __builtin_popcountll(m);

    __syncthreads();

    int gl = lane & 15, g = lane >> 4;
    const float4* Yr = (const float4*)(ylds + wv * 256);
    float4 ya = Yr[gl], yb = Yr[gl + 16], yc = Yr[gl + 32], yd = Yr[gl + 48];

    // na from registers (16-lane group reduce)
    float p = ya.x * ya.x;
    p = fmaf(ya.y, ya.y, p); p = fmaf(ya.z, ya.z, p); p = fmaf(ya.w, ya.w, p);
    p = fmaf(yb.x, yb.x, p); p = fmaf(yb.y, yb.y, p); p = fmaf(yb.z, yb.z, p);
    p = fmaf(yb.w, yb.w, p);
    p = fmaf(yc.x, yc.x, p); p = fmaf(yc.y, yc.y, p); p = fmaf(yc.z, yc.z, p);
    p = fmaf(yc.w, yc.w, p);
    p = fmaf(yd.x, yd.x, p); p = fmaf(yd.y, yd.y, p); p = fmaf(yd.z, yd.z, p);
    p = fmaf(yd.w, yd.w, p);
#pragma unroll
    for (int off = 1; off < 16; off <<= 1) p += __shfl_xor(p, off);
    float na = __fsqrt_rn(p);

    const float* Zb = zt  + ((size_t)(1 - loss) * BB + b) * ((size_t)NPIX * CC);
    const float* zn = zn2 + ((size_t)(1 - loss) * BB + b) * NPIX;

    double ssum = 0.0;
#pragma unroll
    for (int rr = 0; rr < 4; rr++) {
        int mr = (int)((m >> (4 * rr)) & 15ull);
        if (!mr) continue;
        int s   = 4 * rr + g;                 // this group's slot
        bool val = (mr >> g) & 1;
        int j = val ? ((jy0 + (s >> 2)) * 28 + jx0 + (s & 3)) : 0;
        const float4* Z4 = (const float4*)(Zb + (size_t)j * CC);
        float4 za = Z4[gl], zb_ = Z4[gl + 16], zc = Z4[gl + 32], zd = Z4[gl + 48];
        float nb2 = zn[j];
        float dp = ya.x * za.x;
        dp = fmaf(ya.y, za.y, dp); dp = fmaf(ya.z, za.z, dp);
        dp = fmaf(ya.w, za.w, dp);
        dp = fmaf(yb.x, zb_.x, dp); dp = fmaf(yb.y, zb_.y, dp);
        dp = fmaf(yb.z, zb_.z, dp); dp = fmaf(yb.w, zb_.w, dp);
        dp = fmaf(yc.x, zc.x, dp); dp = fmaf(yc.y, zc.y, dp);
        dp = fmaf(yc.z, zc.z, dp); dp = fmaf(yc.w, zc.w, dp);
        dp = fmaf(yd.x, zd.x, dp); dp = fmaf(yd.y, zd.y, dp);
        dp = fmaf(yd.z, zd.z, dp); dp = fmaf(yd.w, zd.w, dp);
#pragma unroll
        for (int off = 1; off < 16; off <<= 1) dp += __shfl_xor(dp, off);
        float den = fmaxf(na * __fsqrt_rn(nb2), 1e-8f);
        float sim = __fdividef(dp, den);
        if (val) ssum += (double)sim;
    }
    // combine the 4 groups (lanes within a group hold identical ssum)
    ssum += __shfl_xor(ssum, 16);
    ssum += __shfl_xor(ssum, 32);

    if (lane == 0) { shs[wv] = ssum; shc[wv] = cnt; }
    __syncthreads();
    if (tid == 0) {
        double s = 0.0; int c = 0;
#pragma unroll
        for (int k = 0; k < 16; k++) { s += shs[k]; c += shc[k]; }
        double* slot = acc + (size_t)(bx & (SLOTS - 1)) * 4;
        atomicAdd(&slot[loss * 2],     s);
        atomicAdd(&slot[loss * 2 + 1], (double)c);
    }
}

// ---------------------------------------------------------------------------
// K3: finalize  loss = -(S0/M0 + S1/M1)  (reduce the 128 slots)
// ---------------------------------------------------------------------------
__global__ void fin_k(const double* __restrict__ acc, float* __restrict__ out) {
    int lane = threadIdx.x;   // 64 threads
    double s0 = 0, m0 = 0, s1 = 0, m1 = 0;
    for (int s = lane; s < SLOTS; s += 64) {
        const double* p = acc + (size_t)s * 4;
        s0 += p[0]; m0 += p[1]; s1 += p[2]; m1 += p[3];
    }
#pragma unroll
    for (int off = 32; off; off >>= 1) {
        s0 += __shfl_xor(s0, off); m0 += __shfl_xor(m0, off);
        s1 += __shfl_xor(s1, off); m1 += __shfl_xor(m1, off);
    }
    if (lane == 0) out[0] = (float)(-(s0 / m0 + s1 / m1));
}

extern "C" void kernel_launch(void* const* d_in, const int* in_sizes, int n_in,
                              void* d_out, int out_size, void* d_ws, size_t ws_size,
                              hipStream_t stream) {
    const float* y1 = (const float*)d_in[0];
    const float* y2 = (const float*)d_in[1];
    const float* z1 = (const float*)d_in[2];
    const float* z2 = (const float*)d_in[3];
    const float* g1 = (const float*)d_in[4];
    const float* g2 = (const float*)d_in[5];
    float* out = (float*)d_out;

    char* ws = (char*)d_ws;
    double* acc = (double*)ws;                         // SLOTS*4 doubles = 4 KB
    float*  zn2 = (float*)(ws + 4096);                 // 2*BNP floats
    float*  zt  = (float*)(ws + 4096 + 2 * BNP * sizeof(float));
    // zt: [2][B][N][C] = 2 * 12,845,056 floats = 102.8 MB

    hipMemsetAsync(acc, 0, SLOTS * 4 * sizeof(double), stream);

    // z transpose + norms: 2 arrays * 64 b * 25 n-tiles = 3200 blocks
    zt_k<<<3200, 256, 0, stream>>>(z1, z2, zt, zn2);

    // pairs: 2 losses * 64 b * 49 i-groups = 6272 blocks x 1024 threads
    pairs_k<<<6272, 1024, 0, stream>>>(y1, y2, zt, zn2, g1, g2, acc);

    fin_k<<<1, 64, 0, stream>>>(acc, out);
}